// Round 9
// baseline (2562.687 us; speedup 1.0000x reference)
//
#include <hip/hip_runtime.h>

// LightGCN propagation: 3x SpMM over fixed COO graph + batched dot epilogue.
// R9: fine sort (p4/epair/rowinfo) ELIMINATED. Coarse partition to 1024
// buckets of 147 nodes; spmm accumulates each bucket in a fp32 LDS tile
// (147 x 65-float padded = 38.2KB) via ds_add_f32, streaming the bucket's
// unsorted edges. 1024 blocks x 512 thr = 4 blocks/CU, 32 waves/CU.
// R8 lessons: no nontemporal on payload (it re-fetched 5x); keep many
// independent edge-gathers per wave. bf16 row storage (R5). Build phase was
// ~160us (= all of spmm); p4 alone ~45 — this removes it structurally.

#define N_USERS 50000
#define N_ITEMS 100000
#define N_NODES 150000
#define N_EDGES 2400000
#define DIM 64
#define BATCH 4096

#define CHUNKS 128
#define CHUNK_EDGES 18750   // 128*18750 = 2400000 exact
#define KB 1024             // coarse buckets
#define NPB 147             // nodes per bucket; 1024*147 = 150528 >= N_NODES
#define LDS_STRIDE 65       // pad: breaks 4-group ds_add bank aliasing
#define CONVB 4688          // ceil(2400000/512) conv blocks

typedef unsigned int uint;
typedef float v2f __attribute__((ext_vector_type(2)));

__device__ __forceinline__ uint pack_bf16(float a, float b) {
    uint ua = __float_as_uint(a), ub = __float_as_uint(b);
    ua = (ua + 0x7FFFu + ((ua >> 16) & 1u)) >> 16;   // RTNE
    ub = (ub + 0x7FFFu + ((ub >> 16) & 1u)) >> 16;
    return ua | (ub << 16);
}

__device__ __forceinline__ v2f unpack_bf16x2(uint w) {
    v2f r;
    r.x = __uint_as_float(w << 16);
    r.y = __uint_as_float(w & 0xFFFF0000u);
    return r;
}

// Fused P1 + conv: blocks [0,CHUNKS) per-chunk 1024-bucket histogram;
// blocks [CHUNKS, CHUNKS+CONVB) convert fp32 tables -> bf16 concat t0.
__global__ __launch_bounds__(512) void p1_hist_conv(
        const int* __restrict__ dst, int* __restrict__ hist,
        const float* __restrict__ emb_user, const float* __restrict__ emb_item,
        uint2* __restrict__ t0) {
    int t = threadIdx.x;
    if (blockIdx.x < CHUNKS) {
        __shared__ int h[KB];
        int c = blockIdx.x;
        h[t] = 0;
        h[t + 512] = 0;
        __syncthreads();
        int base = c * CHUNK_EDGES;
        for (int i = t; i < CHUNK_EDGES; i += 512)
            atomicAdd(&h[(unsigned)dst[base + i] / NPB], 1);
        __syncthreads();
        hist[t * CHUNKS + c] = h[t];              // bucket-major
        hist[(t + 512) * CHUNKS + c] = h[t + 512];
    } else {
        int i = (blockIdx.x - CHUNKS) * 512 + t;  // float4 index, 2.4M total
        if (i < N_NODES * DIM / 4) {
            const int userN4 = N_USERS * DIM / 4; // 800000
            float4 v;
            if (i < userN4) v = ((const float4*)emb_user)[i];
            else            v = ((const float4*)emb_item)[i - userN4];
            t0[i] = make_uint2(pack_bf16(v.x, v.y), pack_bf16(v.z, v.w));
        }
    }
}

// P2a: per-bucket exclusive scan over its 128 chunk counts (in place); totals.
__global__ __launch_bounds__(128) void p2a_scan(int* __restrict__ hist,
                                                int* __restrict__ tot) {
    int b = blockIdx.x, t = threadIdx.x;
    int v = hist[b * CHUNKS + t];
    __shared__ int sm[128];
    sm[t] = v;
    __syncthreads();
    for (int o = 1; o < 128; o <<= 1) {
        int add = (t >= o) ? sm[t - o] : 0;
        __syncthreads();
        sm[t] += add;
        __syncthreads();
    }
    hist[b * CHUNKS + t] = sm[t] - v;   // exclusive offset within bucket
    if (t == 127) tot[b] = sm[t];
}

// P2b: exclusive scan of the 1024 bucket totals -> bucket_base[1025]
__global__ __launch_bounds__(1024) void p2b_scan(const int* __restrict__ tot,
                                                 int* __restrict__ bucket_base) {
    int t = threadIdx.x;
    int v = tot[t];
    __shared__ int sm[1024];
    sm[t] = v;
    __syncthreads();
    for (int o = 1; o < 1024; o <<= 1) {
        int add = (t >= o) ? sm[t - o] : 0;
        __syncthreads();
        sm[t] += add;
        __syncthreads();
    }
    bucket_base[t] = sm[t] - v;
    if (t == 1023) bucket_base[1024] = sm[t];
}

// P3: coarse partition into block-owned per-bucket runs (~18 edges = ~146B
// per run -> full-line L2 assembly). Payload: x = src | dl<<18, y = val bits.
__global__ __launch_bounds__(512) void p3_part(const int* __restrict__ src,
                                               const int* __restrict__ dstA,
                                               const float* __restrict__ vals,
                                               const int* __restrict__ hist,
                                               const int* __restrict__ bucket_base,
                                               int2* __restrict__ coarse) {
    __shared__ int cur[KB];
    int c = blockIdx.x, t = threadIdx.x;
    cur[t] = bucket_base[t] + hist[t * CHUNKS + c];
    cur[t + 512] = bucket_base[t + 512] + hist[(t + 512) * CHUNKS + c];
    __syncthreads();
    int base = c * CHUNK_EDGES;
    for (int i = t; i < CHUNK_EDGES; i += 512) {
        int e = base + i;
        int d = dstA[e];
        int b = (int)((unsigned)d / NPB);
        int dl = d - b * NPB;
        int p = atomicAdd(&cur[b], 1);
        coarse[p] = make_int2(src[e] | (dl << 18), __float_as_int(vals[e]));
    }
}

// SpMM: one block per bucket. fp32 LDS tile (147 rows x 65-float stride),
// stream the bucket's ~2344 unsorted edges: 16-lane group per edge (uint2 =
// 4 dims/lane), 2x unroll -> 64 gathers in flight/block. ds_add_f32 accum.
// Epilogue: pack tile to bf16, contiguous coalesced write.
__global__ __launch_bounds__(512) void spmm_kernel(
        const int2* __restrict__ coarse, const int* __restrict__ bucket_base,
        const uint* __restrict__ xin, uint* __restrict__ xout) {
    extern __shared__ float facc[];     // NPB*65 floats = 38220 B
    int k = blockIdx.x, t = threadIdx.x;
    int base = bucket_base[k];
    int ne = bucket_base[k + 1] - base;
    int nodes0 = k * NPB;
    int nb = min(NPB, N_NODES - nodes0);   // <=0 for tail blocks past N_NODES
    for (int i = t; i < NPB * LDS_STRIDE; i += 512) facc[i] = 0.f;
    __syncthreads();
    int grp = t >> 4;        // edge group 0..31
    int l = t & 15;          // uint2 slot (dims 4l..4l+3)
    for (int i0 = grp; i0 < ne; i0 += 64) {
        int i1 = i0 + 32;
        bool p1 = i1 < ne;
        int2 e0 = coarse[base + i0];
        int2 e1 = coarse[base + (p1 ? i1 : i0)];
        float v0 = __int_as_float(e0.y);
        float v1 = p1 ? __int_as_float(e1.y) : 0.f;
        int dl0 = e0.x >> 18, s0 = e0.x & 0x3FFFF;
        int dl1 = e1.x >> 18, s1 = e1.x & 0x3FFFF;
        uint2 r0 = ((const uint2*)(xin + (size_t)s0 * 32))[l];
        uint2 r1 = ((const uint2*)(xin + (size_t)s1 * 32))[l];
        v2f f00 = unpack_bf16x2(r0.x), f01 = unpack_bf16x2(r0.y);
        v2f f10 = unpack_bf16x2(r1.x), f11 = unpack_bf16x2(r1.y);
        float* w0 = &facc[dl0 * LDS_STRIDE + l * 4];
        float* w1 = &facc[dl1 * LDS_STRIDE + l * 4];
        atomicAdd(&w0[0], v0 * f00.x);
        atomicAdd(&w0[1], v0 * f00.y);
        atomicAdd(&w0[2], v0 * f01.x);
        atomicAdd(&w0[3], v0 * f01.y);
        atomicAdd(&w1[0], v1 * f10.x);
        atomicAdd(&w1[1], v1 * f10.y);
        atomicAdd(&w1[2], v1 * f11.x);
        atomicAdd(&w1[3], v1 * f11.y);
    }
    __syncthreads();
    uint* outp = xout + (size_t)nodes0 * 32;
    for (int i = t; i < nb * 32; i += 512) {
        int dl = i >> 5, m = i & 31;
        outp[i] = pack_bf16(facc[dl * LDS_STRIDE + 2 * m],
                            facc[dl * LDS_STRIDE + 2 * m + 1]);
    }
}

// Fused epilogue: one wave per batch element, lane = dim.
// gamma[b] = dot(x0u+x1u+x2u+x3u, x0i+x1i+x2i+x3i) / 16
__global__ __launch_bounds__(256) void final_kernel(
        const int* __restrict__ users, const int* __restrict__ items,
        const float* __restrict__ emb_user, const float* __restrict__ emb_item,
        const unsigned short* __restrict__ x1, const unsigned short* __restrict__ x2,
        const unsigned short* __restrict__ x3, float* __restrict__ out) {
    int t = blockIdx.x * 256 + threadIdx.x;
    int b = t >> 6;
    int lane = t & 63;
    int un = users[b];
    int in = N_USERS + items[b];
    size_t uo = (size_t)un * DIM + lane;
    size_t io = (size_t)in * DIM + lane;
    float u = emb_user[uo]
            + __uint_as_float((uint)x1[uo] << 16)
            + __uint_as_float((uint)x2[uo] << 16)
            + __uint_as_float((uint)x3[uo] << 16);
    float v = emb_item[(size_t)items[b] * DIM + lane]
            + __uint_as_float((uint)x1[io] << 16)
            + __uint_as_float((uint)x2[io] << 16)
            + __uint_as_float((uint)x3[io] << 16);
    float p = u * v;
#pragma unroll
    for (int o = 32; o > 0; o >>= 1) p += __shfl_down(p, o, 64);
    if (lane == 0) out[b] = p * (1.0f / 16.0f);
}

extern "C" void kernel_launch(void* const* d_in, const int* in_sizes, int n_in,
                              void* d_out, int out_size, void* d_ws, size_t ws_size,
                              hipStream_t stream) {
    const float* emb_user = (const float*)d_in[0];
    const float* emb_item = (const float*)d_in[1];
    const float* vals     = (const float*)d_in[2];
    const int*   src      = (const int*)d_in[3];
    const int*   dst      = (const int*)d_in[4];
    const int*   users    = (const int*)d_in[5];
    const int*   items    = (const int*)d_in[6];
    float* out = (float*)d_out;

    char* ws = (char*)d_ws;
    size_t off = 0;
    auto walloc = [&](size_t bytes) -> void* {
        void* p = ws + off;
        off += (bytes + 255) & ~(size_t)255;
        return p;
    };
    const size_t ROWB = (size_t)N_NODES * DIM * 2;                  // 19.2 MB
    uint* t0          = (uint*)walloc(ROWB);                        // bf16 x0
    uint* x1          = (uint*)walloc(ROWB);
    uint* x2          = (uint*)walloc(ROWB);
    uint* x3          = (uint*)walloc(ROWB);
    int2* coarse      = (int2*)walloc((size_t)N_EDGES * 8);         // 19.2 MB
    int*  hist        = (int*) walloc((size_t)CHUNKS * KB * 4);     // 0.5 MB
    int*  tot         = (int*) walloc((size_t)KB * 4);
    int*  bucket_base = (int*) walloc((size_t)(KB + 1) * 4);

    // CSR-free build: coarse partition only (+ fused bf16 conversion)
    p1_hist_conv<<<CHUNKS + CONVB, 512, 0, stream>>>(dst, hist, emb_user, emb_item, (uint2*)t0);
    p2a_scan<<<KB, 128, 0, stream>>>(hist, tot);
    p2b_scan<<<1, 1024, 0, stream>>>(tot, bucket_base);
    p3_part<<<CHUNKS, 512, 0, stream>>>(src, dst, vals, hist, bucket_base, coarse);

    const size_t smem = (size_t)NPB * LDS_STRIDE * 4;  // 38220 B
    spmm_kernel<<<KB, 512, smem, stream>>>(coarse, bucket_base, t0, x1);
    spmm_kernel<<<KB, 512, smem, stream>>>(coarse, bucket_base, x1, x2);
    spmm_kernel<<<KB, 512, smem, stream>>>(coarse, bucket_base, x2, x3);

    // fused epilogue
    final_kernel<<<(BATCH * DIM) / 256, 256, 0, stream>>>(
        users, items, emb_user, emb_item,
        (const unsigned short*)x1, (const unsigned short*)x2, (const unsigned short*)x3, out);
}

// Round 10
// 287.829 us; speedup vs baseline: 8.9035x; 8.9035x over previous
//
#include <hip/hip_runtime.h>

// LightGCN propagation: 3x SpMM over fixed COO graph + batched dot epilogue.
// R10: (a) spmm reverted to proven R6 form (8 groups x 8 lanes, uint4/lane,
// 2x unroll; R8 node-per-group and R9 LDS-atomic variants both regressed —
// R9's ds_add scatter hit 300K bank-conflict cycles). (b) Layer 3 computes
// only the ~8192 batch rows (full 150K-row spmm was 57us; only batch rows
// are ever read) via per-wave CSR gather + fused x0+x1+x2 add. (c) p4 scans
// rewritten as wave-shuffle scans (6 barriers, was ~36); p2b restored.
// bf16 row storage (R5): compulsory fabric traffic = 8 XCD x 19.2MB/layer.

#define N_USERS 50000
#define N_ITEMS 100000
#define N_NODES 150000
#define N_EDGES 2400000
#define DIM 64
#define BATCH 4096

#define CHUNKS 512
#define CHUNK_EDGES 4688   // 512*4688 = 2400256 >= N_EDGES
#define KB 256             // coarse buckets
#define NPB 586            // nodes per bucket; 256*586 = 150016 >= N_NODES
#define CONVB ((N_NODES * DIM / 4) / 256)   // 9375 conv blocks

typedef unsigned int uint;
typedef float v2f __attribute__((ext_vector_type(2)));

__device__ __forceinline__ uint pack_bf16(float a, float b) {
    uint ua = __float_as_uint(a), ub = __float_as_uint(b);
    ua = (ua + 0x7FFFu + ((ua >> 16) & 1u)) >> 16;   // RTNE
    ub = (ub + 0x7FFFu + ((ub >> 16) & 1u)) >> 16;
    return ua | (ub << 16);
}

__device__ __forceinline__ v2f unpack_bf16x2(uint w) {
    v2f r;
    r.x = __uint_as_float(w << 16);
    r.y = __uint_as_float(w & 0xFFFF0000u);
    return r;
}

// Fused P1 + conv: blocks [0,CHUNKS) per-chunk coarse histogram;
// blocks [CHUNKS, CHUNKS+CONVB) convert fp32 tables -> bf16 concat t0.
__global__ __launch_bounds__(256) void p1_hist_conv(
        const int* __restrict__ dst, int* __restrict__ hist,
        const float* __restrict__ emb_user, const float* __restrict__ emb_item,
        uint2* __restrict__ t0) {
    int t = threadIdx.x;
    if (blockIdx.x < CHUNKS) {
        __shared__ int h[KB];
        int c = blockIdx.x;
        h[t] = 0;
        __syncthreads();
        int base = c * CHUNK_EDGES;
        for (int i = t; i < CHUNK_EDGES; i += 256) {
            int e = base + i;
            if (e < N_EDGES) atomicAdd(&h[(unsigned)dst[e] / NPB], 1);
        }
        __syncthreads();
        hist[t * CHUNKS + c] = h[t];   // bucket-major
    } else {
        int i = (blockIdx.x - CHUNKS) * 256 + t;       // float4 index, 2.4M total
        const int userN4 = N_USERS * DIM / 4;          // 800000
        float4 v;
        if (i < userN4) v = ((const float4*)emb_user)[i];
        else            v = ((const float4*)emb_item)[i - userN4];
        t0[i] = make_uint2(pack_bf16(v.x, v.y), pack_bf16(v.z, v.w));
    }
}

// P2a: per-bucket exclusive scan over its 512 chunk counts; emit totals.
__global__ __launch_bounds__(256) void p2a_scan(int* __restrict__ hist,
                                                int* __restrict__ tot) {
    int b = blockIdx.x, t = threadIdx.x;
    int i0 = b * CHUNKS + 2 * t;
    int v0 = hist[i0], v1 = hist[i0 + 1];
    int s = v0 + v1;
    __shared__ int sm[256];
    sm[t] = s;
    __syncthreads();
    for (int o = 1; o < 256; o <<= 1) {
        int add = (t >= o) ? sm[t - o] : 0;
        __syncthreads();
        sm[t] += add;
        __syncthreads();
    }
    int excl = sm[t] - s;
    hist[i0] = excl;
    hist[i0 + 1] = excl + v0;
    if (t == 255) tot[b] = excl + s;
}

// P2b: exclusive scan of the 256 bucket totals -> bucket_base[257]
__global__ __launch_bounds__(256) void p2b_scan(const int* __restrict__ tot,
                                                int* __restrict__ bucket_base) {
    int t = threadIdx.x;
    int v = tot[t];
    __shared__ int sm[256];
    sm[t] = v;
    __syncthreads();
    for (int o = 1; o < 256; o <<= 1) {
        int add = (t >= o) ? sm[t - o] : 0;
        __syncthreads();
        sm[t] += add;
        __syncthreads();
    }
    bucket_base[t] = sm[t] - v;
    if (t == 255) bucket_base[256] = sm[t];
}

// P3: coarse partition into block-owned per-bucket runs.
// Payload packed: x = src | dst_local<<18, y = val bits.
__global__ __launch_bounds__(256) void p3_part(const int* __restrict__ src,
                                               const int* __restrict__ dstA,
                                               const float* __restrict__ vals,
                                               const int* __restrict__ hist,
                                               const int* __restrict__ bucket_base,
                                               int2* __restrict__ coarse) {
    __shared__ int cur[KB];
    int c = blockIdx.x, t = threadIdx.x;
    cur[t] = bucket_base[t] + hist[t * CHUNKS + c];
    __syncthreads();
    int base = c * CHUNK_EDGES;
    for (int i = t; i < CHUNK_EDGES; i += 256) {
        int e = base + i;
        if (e < N_EDGES) {
            int d = dstA[e];
            int b = (int)((unsigned)d / NPB);
            int dl = d - b * NPB;
            int p = atomicAdd(&cur[b], 1);
            coarse[p] = make_int2(src[e] | (dl << 18), __float_as_int(vals[e]));
        }
    }
}

// P4: fine sort within each bucket + emit packed rowinfo (start | deg<<22).
// 1024 threads; wave-shuffle scans (6 barriers total).
__global__ __launch_bounds__(1024) void p4_fine(const int2* __restrict__ coarse,
                                                const int* __restrict__ bucket_base,
                                                int2* __restrict__ epair,
                                                uint* __restrict__ rowinfo) {
    int k = blockIdx.x, t = threadIdx.x;
    __shared__ int cnt[768];
    __shared__ int rs[768];
    __shared__ int wsum[12];
    if (t < 768) cnt[t] = 0;
    __syncthreads();
    int base = bucket_base[k];
    int ne = bucket_base[k + 1] - base;
    for (int i = t; i < ne; i += 1024)
        atomicAdd(&cnt[coarse[base + i].x >> 18], 1);
    __syncthreads();
    // exclusive scan over 768 counters: per-wave shfl scan + wave-sum combine
    int wid = t >> 6, lane = t & 63;
    if (t < 768) {
        int v = cnt[t];
        int incl = v;
#pragma unroll
        for (int o = 1; o < 64; o <<= 1) {
            int add = __shfl_up(incl, o, 64);
            if (lane >= o) incl += add;
        }
        if (lane == 63) wsum[wid] = incl;
        rs[t] = incl - v;        // exclusive within wave
    }
    __syncthreads();
    if (t < 64) {
        int v = (lane < 12) ? wsum[lane] : 0;
        int incl = v;
#pragma unroll
        for (int o = 1; o < 16; o <<= 1) {
            int add = __shfl_up(incl, o, 64);
            if (lane >= o) incl += add;
        }
        if (lane < 12) wsum[lane] = incl - v;   // exclusive wave offset
    }
    __syncthreads();
    if (t < 768) rs[t] += wsum[wid];
    __syncthreads();
    int nodes0 = k * NPB;
    int nb = min(NPB, N_NODES - nodes0);
    if (t < nb)
        rowinfo[nodes0 + t] = (uint)(base + rs[t]) | ((uint)cnt[t] << 22);
    __syncthreads();
    if (t < 768) cnt[t] = rs[t];      // cnt becomes cursor
    __syncthreads();
    for (int i = t; i < ne; i += 1024) {
        int2 ev = coarse[base + i];
        int dl = ev.x >> 18;
        int p = atomicAdd(&cnt[dl], 1);
        epair[base + p] = make_int2(ev.x & 0x3FFFF, ev.y);
    }
}

// SpMM over bf16 rows (32 uints = 128B/row). R6 form: one wave per node;
// 8 groups x 8 lanes; 2x unrolled -> 16 edges in flight. Lane l = uint4
// (dims 8l..8l+7); shfl_xor cross-group reduce; group 0 packs + writes.
__global__ __launch_bounds__(256) void spmm_kernel(
        const uint* __restrict__ rowinfo, const int2* __restrict__ epair,
        const uint* __restrict__ xin, uint* __restrict__ xout) {
    int n = (blockIdx.x * 256 + threadIdx.x) >> 6;   // 150000 = 4*37500 exact
    int lane = threadIdx.x & 63;
    int g = lane >> 3;        // edge group 0..7
    int l = lane & 7;         // uint4 slot within row
    uint ri = rowinfo[n];
    int s = (int)(ri & 0x3FFFFFu);
    int e = s + (int)(ri >> 22);
    v2f a0 = {0.f, 0.f}, a1 = {0.f, 0.f}, a2 = {0.f, 0.f}, a3 = {0.f, 0.f};
    for (int j0 = s + g; j0 < e; j0 += 16) {
        int j1 = j0 + 8;
        bool p1 = j1 < e;
        int2 ev0 = epair[j0];
        int2 ev1 = epair[p1 ? j1 : j0];
        float v0 = __int_as_float(ev0.y);
        float v1 = p1 ? __int_as_float(ev1.y) : 0.f;
        uint4 r0 = ((const uint4*)(xin + (size_t)ev0.x * 32))[l];
        uint4 r1 = ((const uint4*)(xin + (size_t)ev1.x * 32))[l];
        a0 += v0 * unpack_bf16x2(r0.x);
        a1 += v0 * unpack_bf16x2(r0.y);
        a2 += v0 * unpack_bf16x2(r0.z);
        a3 += v0 * unpack_bf16x2(r0.w);
        a0 += v1 * unpack_bf16x2(r1.x);
        a1 += v1 * unpack_bf16x2(r1.y);
        a2 += v1 * unpack_bf16x2(r1.z);
        a3 += v1 * unpack_bf16x2(r1.w);
    }
#pragma unroll
    for (int off = 8; off < 64; off <<= 1) {
        a0.x += __shfl_xor(a0.x, off, 64);
        a0.y += __shfl_xor(a0.y, off, 64);
        a1.x += __shfl_xor(a1.x, off, 64);
        a1.y += __shfl_xor(a1.y, off, 64);
        a2.x += __shfl_xor(a2.x, off, 64);
        a2.y += __shfl_xor(a2.y, off, 64);
        a3.x += __shfl_xor(a3.x, off, 64);
        a3.y += __shfl_xor(a3.y, off, 64);
    }
    if (g == 0) {
        uint4 o;
        o.x = pack_bf16(a0.x, a0.y);
        o.y = pack_bf16(a1.x, a1.y);
        o.z = pack_bf16(a2.x, a2.y);
        o.w = pack_bf16(a3.x, a3.y);
        ((uint4*)(xout + (size_t)n * 32))[l] = o;
    }
}

// Layer-3 restricted to batch rows: one wave per batch node (2*BATCH waves).
// Wave = 4 groups x 16 lanes (uint2/lane, 4x unroll = 16 edges in flight):
// x3[n] = sum val*x2[src]; then add x0 (fp32 table) + x1 + x2 (bf16) and
// store the full fp32 summed row to rows[w][64].
__global__ __launch_bounds__(256) void batch_row_kernel(
        const int* __restrict__ users, const int* __restrict__ items,
        const float* __restrict__ emb_user, const float* __restrict__ emb_item,
        const uint* __restrict__ x1, const uint* __restrict__ x2,
        const uint* __restrict__ rowinfo, const int2* __restrict__ epair,
        float4* __restrict__ rows) {
    int w = (blockIdx.x * 256 + threadIdx.x) >> 6;   // 0..2*BATCH-1
    int lane = threadIdx.x & 63;
    int g = lane >> 4;
    int l = lane & 15;        // uint2 slot: dims 4l..4l+3
    bool isU = w < BATCH;
    int b = isU ? w : w - BATCH;
    int idx = isU ? users[b] : items[b];
    int n = isU ? idx : N_USERS + idx;
    uint ri = rowinfo[n];
    int s = (int)(ri & 0x3FFFFFu);
    int e = s + (int)(ri >> 22);
    v2f a0 = {0.f, 0.f}, a1 = {0.f, 0.f};
    for (int j0 = s + g; j0 < e; j0 += 16) {
        int2 ev[4];
        float vv[4];
        uint2 rr[4];
#pragma unroll
        for (int u = 0; u < 4; ++u) {
            int j = j0 + 4 * u;
            bool p = (u == 0) || (j < e);
            ev[u] = epair[p ? j : j0];
            vv[u] = p ? __int_as_float(ev[u].y) : 0.f;
        }
#pragma unroll
        for (int u = 0; u < 4; ++u)
            rr[u] = ((const uint2*)(x2 + (size_t)ev[u].x * 32))[l];
#pragma unroll
        for (int u = 0; u < 4; ++u) {
            a0 += vv[u] * unpack_bf16x2(rr[u].x);
            a1 += vv[u] * unpack_bf16x2(rr[u].y);
        }
    }
#pragma unroll
    for (int off = 16; off < 64; off <<= 1) {
        a0.x += __shfl_xor(a0.x, off, 64);
        a0.y += __shfl_xor(a0.y, off, 64);
        a1.x += __shfl_xor(a1.x, off, 64);
        a1.y += __shfl_xor(a1.y, off, 64);
    }
    if (g == 0) {
        const float* t0row = isU ? (emb_user + (size_t)idx * DIM)
                                 : (emb_item + (size_t)idx * DIM);
        float4 x0 = ((const float4*)t0row)[l];
        uint2 w1 = ((const uint2*)(x1 + (size_t)n * 32))[l];
        uint2 w2 = ((const uint2*)(x2 + (size_t)n * 32))[l];
        v2f b10 = unpack_bf16x2(w1.x), b11 = unpack_bf16x2(w1.y);
        v2f b20 = unpack_bf16x2(w2.x), b21 = unpack_bf16x2(w2.y);
        float4 r;
        r.x = x0.x + b10.x + b20.x + a0.x;
        r.y = x0.y + b10.y + b20.y + a0.y;
        r.z = x0.z + b11.x + b21.x + a1.x;
        r.w = x0.w + b11.y + b21.y + a1.y;
        rows[(size_t)w * 16 + l] = r;
    }
}

// gamma[b] = dot(rows[b], rows[BATCH+b]) / 16
__global__ __launch_bounds__(256) void dot_kernel(const float* __restrict__ rows,
                                                  float* __restrict__ out) {
    int t = blockIdx.x * 256 + threadIdx.x;
    int b = t >> 6;
    int lane = t & 63;
    float p = rows[(size_t)b * DIM + lane] * rows[(size_t)(BATCH + b) * DIM + lane];
#pragma unroll
    for (int o = 32; o > 0; o >>= 1) p += __shfl_down(p, o, 64);
    if (lane == 0) out[b] = p * (1.0f / 16.0f);
}

extern "C" void kernel_launch(void* const* d_in, const int* in_sizes, int n_in,
                              void* d_out, int out_size, void* d_ws, size_t ws_size,
                              hipStream_t stream) {
    const float* emb_user = (const float*)d_in[0];
    const float* emb_item = (const float*)d_in[1];
    const float* vals     = (const float*)d_in[2];
    const int*   src      = (const int*)d_in[3];
    const int*   dst      = (const int*)d_in[4];
    const int*   users    = (const int*)d_in[5];
    const int*   items    = (const int*)d_in[6];
    float* out = (float*)d_out;

    char* ws = (char*)d_ws;
    size_t off = 0;
    auto walloc = [&](size_t bytes) -> void* {
        void* p = ws + off;
        off += (bytes + 255) & ~(size_t)255;
        return p;
    };
    const size_t ROWB = (size_t)N_NODES * DIM * 2;                  // 19.2 MB
    uint* t0          = (uint*)walloc(ROWB);                        // bf16 x0
    uint* x1          = (uint*)walloc(ROWB);
    uint* x2          = (uint*)walloc(ROWB);
    int2* coarse      = (int2*)walloc((size_t)N_EDGES * 8);         // 19.2 MB
    int2* epair       = (int2*)walloc((size_t)N_EDGES * 8);         // 19.2 MB
    int*  hist        = (int*) walloc((size_t)CHUNKS * KB * 4);     // 0.5 MB
    int*  tot         = (int*) walloc((size_t)KB * 4);
    int*  bucket_base = (int*) walloc((size_t)(KB + 1) * 4);
    uint* rowinfo     = (uint*)walloc((size_t)N_NODES * 4);
    // rows (2*BATCH*64 fp32 = 2MB) aliases coarse: coarse dead after p4,
    // rows first written by batch_row_kernel (after all spmm layers).
    float4* rows = (float4*)coarse;

    // CSR build (+ fused bf16 conversion)
    p1_hist_conv<<<CHUNKS + CONVB, 256, 0, stream>>>(dst, hist, emb_user, emb_item, (uint2*)t0);
    p2a_scan<<<KB, 256, 0, stream>>>(hist, tot);
    p2b_scan<<<1, 256, 0, stream>>>(tot, bucket_base);
    p3_part<<<CHUNKS, 256, 0, stream>>>(src, dst, vals, hist, bucket_base, coarse);
    p4_fine<<<KB, 1024, 0, stream>>>(coarse, bucket_base, epair, rowinfo);

    int sblocks = N_NODES / 4;  // 37500, one wave per node
    spmm_kernel<<<sblocks, 256, 0, stream>>>(rowinfo, epair, t0, x1);
    spmm_kernel<<<sblocks, 256, 0, stream>>>(rowinfo, epair, x1, x2);

    // Layer 3 only at batch rows, fused with the layer-sum; then dot.
    batch_row_kernel<<<(2 * BATCH) / 4, 256, 0, stream>>>(
        users, items, emb_user, emb_item, x1, x2, rowinfo, epair, rows);
    dot_kernel<<<(BATCH * 64) / 256, 256, 0, stream>>>((const float*)rows, out);
}